// Round 1
// baseline (731.635 us; speedup 1.0000x reference)
//
#include <hip/hip_runtime.h>
#include <hip/hip_bf16.h>

typedef _Float16 f16x8 __attribute__((ext_vector_type(8)));
typedef float f32x4 __attribute__((ext_vector_type(4)));

#define N_ROWS 4096
#define F_DIM 64
#define BATCH 4
#define EMPF 0.1f
#define EMPD 0.1
#define ZEROV 9e-15f
#define WINDOW 2e-4f
#define LIST_CAP (1u << 20)

// ---------------- Kernel 1: xw = x*w, normalize, split fp32 -> f16 hi/lo ----
__global__ __launch_bounds__(256) void normalize_split_kernel(
    const float* __restrict__ x, const float* __restrict__ w,
    _Float16* __restrict__ hi, _Float16* __restrict__ lo,
    unsigned* __restrict__ counter) {
  if (blockIdx.x == 0 && threadIdx.x == 0) *counter = 0;  // zeroed before kernel2 runs
  const int lane = threadIdx.x & 63;
  const int wid = threadIdx.x >> 6;
  const int rg = blockIdx.x * 4 + wid;          // global row 0..16383 (b*4096+n)
  const int n = rg & (N_ROWS - 1);
  const float xv = x[rg * F_DIM + lane];
  const float wv = w[n * F_DIM + lane];
  const float p = xv * wv;
  float s = p * p;
#pragma unroll
  for (int off = 32; off >= 1; off >>= 1) s += __shfl_xor(s, off, 64);
  const float nrm = fmaxf(sqrtf(s), 1e-8f);
  const float xn = p / nrm;
  const _Float16 h = (_Float16)xn;
  const float rem = xn - (float)h;
  hi[rg * F_DIM + lane] = h;
  lo[rg * F_DIM + lane] = (_Float16)rem;
}

// ---------------- Kernel 2: tiled MFMA Gram + threshold epilogue ------------
// Block = 256 threads = 4 waves (2x2), tile 128x128, wave tile 64x64.
// cos = hi*hi + hi*lo + lo*hi  (lo*lo ~ 2^-24, dropped) -> err ~1e-6.
__global__ __launch_bounds__(256) void gram_kernel(
    const _Float16* __restrict__ hi, const _Float16* __restrict__ lo,
    float* __restrict__ out, unsigned* __restrict__ counter,
    unsigned* __restrict__ list) {
  const int lane = threadIdx.x & 63;
  const int wid = threadIdx.x >> 6;
  const int wm = wid >> 1, wn = wid & 1;
  const int b = blockIdx.z;
  const int row0 = blockIdx.x * 128 + wm * 64;
  const int col0 = blockIdx.y * 128 + wn * 64;
  const int rbase = b * N_ROWS;

  const int lr = lane & 15;         // fragment row
  const int lk = (lane >> 4) * 8;   // fragment k offset

  f32x4 acc[4][4] = {};

#pragma unroll
  for (int kf = 0; kf < 2; ++kf) {
    f16x8 ah[4], al[4], bh[4], bl[4];
#pragma unroll
    for (int i = 0; i < 4; ++i) {
      const int ra = (rbase + row0 + i * 16 + lr) * F_DIM + kf * 32 + lk;
      ah[i] = *(const f16x8*)(hi + ra);
      al[i] = *(const f16x8*)(lo + ra);
      const int rb = (rbase + col0 + i * 16 + lr) * F_DIM + kf * 32 + lk;
      bh[i] = *(const f16x8*)(hi + rb);
      bl[i] = *(const f16x8*)(lo + rb);
    }
#pragma unroll
    for (int i = 0; i < 4; ++i) {
#pragma unroll
      for (int j = 0; j < 4; ++j) {
        acc[i][j] = __builtin_amdgcn_mfma_f32_16x16x32_f16(ah[i], bh[j], acc[i][j], 0, 0, 0);
        acc[i][j] = __builtin_amdgcn_mfma_f32_16x16x32_f16(ah[i], bl[j], acc[i][j], 0, 0, 0);
        acc[i][j] = __builtin_amdgcn_mfma_f32_16x16x32_f16(al[i], bh[j], acc[i][j], 0, 0, 0);
      }
    }
  }

  // Epilogue: C/D layout (16x16x32): col = lane&15, row = (lane>>4)*4 + reg
  const int orow = (lane >> 4) * 4;
  const int ocol = lane & 15;
#pragma unroll
  for (int i = 0; i < 4; ++i) {
#pragma unroll
    for (int j = 0; j < 4; ++j) {
#pragma unroll
      for (int r = 0; r < 4; ++r) {
        const int row = row0 + i * 16 + orow + r;
        const int col = col0 + j * 16 + ocol;
        const float v = acc[i][j][r];
        if (fabsf(v - EMPF) < WINDOW) {
          const unsigned pos = atomicAdd(counter, 1u);
          if (pos < LIST_CAP)
            list[pos] = ((unsigned)b << 24) | ((unsigned)row << 12) | (unsigned)col;
        }
        const size_t oi = ((size_t)b << 24) + ((size_t)row << 12) + (size_t)col;
        out[oi] = (v > EMPF) ? v : ZEROV;
      }
    }
  }
}

// ---------------- Kernel 3: fp64 exact recompute of near-threshold elems ----
__global__ __launch_bounds__(256) void refine_kernel(
    const float* __restrict__ x, const float* __restrict__ w,
    float* __restrict__ out, const unsigned* __restrict__ counter,
    const unsigned* __restrict__ list) {
  const unsigned cnt0 = *counter;
  const unsigned count = cnt0 < LIST_CAP ? cnt0 : LIST_CAP;
  const int lane = threadIdx.x & 63;
  const unsigned wgid = blockIdx.x * (blockDim.x >> 6) + (threadIdx.x >> 6);
  const unsigned nw = gridDim.x * (blockDim.x >> 6);
  for (unsigned e = wgid; e < count; e += nw) {
    const unsigned ent = list[e];
    const int b = (int)(ent >> 24);
    const int i = (int)((ent >> 12) & 4095);
    const int j = (int)(ent & 4095);
    const double wi = (double)w[i * F_DIM + lane];
    const double wj = (double)w[j * F_DIM + lane];
    const double xi = (double)x[(b * N_ROWS + i) * F_DIM + lane];
    const double xj = (double)x[(b * N_ROWS + j) * F_DIM + lane];
    const double pi = xi * wi;
    const double pj = xj * wj;
    double si = pi * pi, sj = pj * pj, sij = pi * pj;
#pragma unroll
    for (int off = 32; off >= 1; off >>= 1) {
      si += __shfl_xor(si, off, 64);
      sj += __shfl_xor(sj, off, 64);
      sij += __shfl_xor(sij, off, 64);
    }
    if (lane == 0) {
      const double ni = fmax(sqrt(si), 1e-8);
      const double nj = fmax(sqrt(sj), 1e-8);
      const double c = sij / (ni * nj);
      const double res = (c > EMPD) ? c : (double)ZEROV;
      out[((size_t)b << 24) + ((size_t)i << 12) + (size_t)j] = (float)res;
    }
  }
}

extern "C" void kernel_launch(void* const* d_in, const int* in_sizes, int n_in,
                              void* d_out, int out_size, void* d_ws, size_t ws_size,
                              hipStream_t stream) {
  const float* x = (const float*)d_in[0];
  const float* w = (const float*)d_in[1];
  float* out = (float*)d_out;

  char* ws = (char*)d_ws;
  _Float16* hi = (_Float16*)ws;                                    // 2 MB
  _Float16* lo = (_Float16*)(ws + (size_t)16384 * 64 * 2);         // 2 MB
  unsigned* counter = (unsigned*)(ws + (size_t)4 * 1024 * 1024);   // 4 B (pad 256)
  unsigned* list = (unsigned*)(ws + (size_t)4 * 1024 * 1024 + 256);// 4 MB

  normalize_split_kernel<<<4096, 256, 0, stream>>>(x, w, hi, lo, counter);
  gram_kernel<<<dim3(32, 32, 4), 256, 0, stream>>>(hi, lo, out, counter, list);
  refine_kernel<<<2048, 256, 0, stream>>>(x, w, out, counter, list);
}

// Round 2
// 130.539 us; speedup vs baseline: 5.6047x; 5.6047x over previous
//
#include <hip/hip_runtime.h>
#include <hip/hip_bf16.h>

typedef _Float16 f16x8 __attribute__((ext_vector_type(8)));
typedef float f32x4 __attribute__((ext_vector_type(4)));

#define N_ROWS 4096
#define F_DIM 64
#define BATCH 4
#define EMPF 0.1f
#define EMPD 0.1
#define ZEROV 9e-15f
#define WINDOW 2e-4f
#define REG_CAP 256u      // per-block flagged-entry slots; E[count]=15, P(>256)~e^-200
#define N_BLOCKS 4096     // 32*32*4 gram blocks

// ---------------- Kernel 1: xw = x*w, normalize, split fp32 -> f16 hi/lo ----
__global__ __launch_bounds__(256) void normalize_split_kernel(
    const float* __restrict__ x, const float* __restrict__ w,
    _Float16* __restrict__ hi, _Float16* __restrict__ lo) {
  const int lane = threadIdx.x & 63;
  const int wid = threadIdx.x >> 6;
  const int rg = blockIdx.x * 4 + wid;          // global row 0..16383 (b*4096+n)
  const int n = rg & (N_ROWS - 1);
  const float xv = x[rg * F_DIM + lane];
  const float wv = w[n * F_DIM + lane];
  const float p = xv * wv;
  float s = p * p;
#pragma unroll
  for (int off = 32; off >= 1; off >>= 1) s += __shfl_xor(s, off, 64);
  const float nrm = fmaxf(sqrtf(s), 1e-8f);
  const float xn = p / nrm;
  const _Float16 h = (_Float16)xn;
  const float rem = xn - (float)h;
  hi[rg * F_DIM + lane] = h;
  lo[rg * F_DIM + lane] = (_Float16)rem;
}

// ---------------- Kernel 2: tiled MFMA Gram + threshold epilogue ------------
// Block = 256 threads = 4 waves (2x2), tile 128x128, wave tile 64x64.
// cos = hi*hi + hi*lo + lo*hi  (lo*lo ~ 2^-24, dropped) -> err ~1e-6.
// Near-threshold elements go to a PER-BLOCK region via an LDS counter —
// no global atomics (R1: 62K same-address device atomics serialized ~650us).
__global__ __launch_bounds__(256) void gram_kernel(
    const _Float16* __restrict__ hi, const _Float16* __restrict__ lo,
    float* __restrict__ out, unsigned* __restrict__ cnt,
    unsigned* __restrict__ regions) {
  __shared__ unsigned lds_cnt;
  if (threadIdx.x == 0) lds_cnt = 0;
  __syncthreads();

  const int lane = threadIdx.x & 63;
  const int wid = threadIdx.x >> 6;
  const int wm = wid >> 1, wn = wid & 1;
  const int b = blockIdx.z;
  const int row0 = blockIdx.x * 128 + wm * 64;
  const int col0 = blockIdx.y * 128 + wn * 64;
  const int rbase = b * N_ROWS;
  const unsigned bid =
      ((unsigned)blockIdx.z * gridDim.y + blockIdx.y) * gridDim.x + blockIdx.x;
  unsigned* __restrict__ region = regions + (size_t)bid * REG_CAP;

  const int lr = lane & 15;         // fragment row
  const int lk = (lane >> 4) * 8;   // fragment k offset

  f32x4 acc[4][4] = {};

#pragma unroll
  for (int kf = 0; kf < 2; ++kf) {
    f16x8 ah[4], al[4], bh[4], bl[4];
#pragma unroll
    for (int i = 0; i < 4; ++i) {
      const int ra = (rbase + row0 + i * 16 + lr) * F_DIM + kf * 32 + lk;
      ah[i] = *(const f16x8*)(hi + ra);
      al[i] = *(const f16x8*)(lo + ra);
      const int rb = (rbase + col0 + i * 16 + lr) * F_DIM + kf * 32 + lk;
      bh[i] = *(const f16x8*)(hi + rb);
      bl[i] = *(const f16x8*)(lo + rb);
    }
#pragma unroll
    for (int i = 0; i < 4; ++i) {
#pragma unroll
      for (int j = 0; j < 4; ++j) {
        acc[i][j] = __builtin_amdgcn_mfma_f32_16x16x32_f16(ah[i], bh[j], acc[i][j], 0, 0, 0);
        acc[i][j] = __builtin_amdgcn_mfma_f32_16x16x32_f16(ah[i], bl[j], acc[i][j], 0, 0, 0);
        acc[i][j] = __builtin_amdgcn_mfma_f32_16x16x32_f16(al[i], bh[j], acc[i][j], 0, 0, 0);
      }
    }
  }

  // Epilogue: C/D layout (16x16x32): col = lane&15, row = (lane>>4)*4 + reg
  const int orow = (lane >> 4) * 4;
  const int ocol = lane & 15;
#pragma unroll
  for (int i = 0; i < 4; ++i) {
#pragma unroll
    for (int j = 0; j < 4; ++j) {
#pragma unroll
      for (int r = 0; r < 4; ++r) {
        const int row = row0 + i * 16 + orow + r;
        const int col = col0 + j * 16 + ocol;
        const float v = acc[i][j][r];
        if (fabsf(v - EMPF) < WINDOW) {
          const unsigned pos = atomicAdd(&lds_cnt, 1u);   // LDS atomic: ~cycles
          if (pos < REG_CAP)
            region[pos] = ((unsigned)b << 24) | ((unsigned)row << 12) | (unsigned)col;
        }
        const size_t oi = ((size_t)b << 24) + ((size_t)row << 12) + (size_t)col;
        out[oi] = (v > EMPF) ? v : ZEROV;
      }
    }
  }

  __syncthreads();
  if (threadIdx.x == 0) cnt[bid] = lds_cnt < REG_CAP ? lds_cnt : REG_CAP;
}

// ---------------- Kernel 3: fp64 exact recompute of near-threshold elems ----
// One wave per block-region (4096 regions, ~15 entries each).
__global__ __launch_bounds__(256) void refine_kernel(
    const float* __restrict__ x, const float* __restrict__ w,
    float* __restrict__ out, const unsigned* __restrict__ cnt,
    const unsigned* __restrict__ regions) {
  const int lane = threadIdx.x & 63;
  const unsigned wg0 = blockIdx.x * (blockDim.x >> 6) + (threadIdx.x >> 6);
  const unsigned nw = gridDim.x * (blockDim.x >> 6);
  for (unsigned rgn = wg0; rgn < N_BLOCKS; rgn += nw) {
    const unsigned count = cnt[rgn];
    const unsigned* __restrict__ region = regions + (size_t)rgn * REG_CAP;
    for (unsigned e = 0; e < count; ++e) {
      const unsigned ent = region[e];
      const int b = (int)(ent >> 24);
      const int i = (int)((ent >> 12) & 4095);
      const int j = (int)(ent & 4095);
      const double wi = (double)w[i * F_DIM + lane];
      const double wj = (double)w[j * F_DIM + lane];
      const double xi = (double)x[(b * N_ROWS + i) * F_DIM + lane];
      const double xj = (double)x[(b * N_ROWS + j) * F_DIM + lane];
      const double pi = xi * wi;
      const double pj = xj * wj;
      double si = pi * pi, sj = pj * pj, sij = pi * pj;
#pragma unroll
      for (int off = 32; off >= 1; off >>= 1) {
        si += __shfl_xor(si, off, 64);
        sj += __shfl_xor(sj, off, 64);
        sij += __shfl_xor(sij, off, 64);
      }
      if (lane == 0) {
        const double ni = fmax(sqrt(si), 1e-8);
        const double nj = fmax(sqrt(sj), 1e-8);
        const double c = sij / (ni * nj);
        const double res = (c > EMPD) ? c : (double)ZEROV;
        out[((size_t)b << 24) + ((size_t)i << 12) + (size_t)j] = (float)res;
      }
    }
  }
}

extern "C" void kernel_launch(void* const* d_in, const int* in_sizes, int n_in,
                              void* d_out, int out_size, void* d_ws, size_t ws_size,
                              hipStream_t stream) {
  const float* x = (const float*)d_in[0];
  const float* w = (const float*)d_in[1];
  float* out = (float*)d_out;

  char* ws = (char*)d_ws;
  _Float16* hi = (_Float16*)ws;                                    // 2 MB
  _Float16* lo = (_Float16*)(ws + (size_t)16384 * 64 * 2);         // 2 MB
  unsigned* cnt = (unsigned*)(ws + (size_t)4 * 1024 * 1024);       // 16 KB
  unsigned* regions = (unsigned*)(ws + (size_t)4 * 1024 * 1024 + 16384); // 4 MB

  normalize_split_kernel<<<4096, 256, 0, stream>>>(x, w, hi, lo);
  gram_kernel<<<dim3(32, 32, 4), 256, 0, stream>>>(hi, lo, out, cnt, regions);
  refine_kernel<<<1024, 256, 0, stream>>>(x, w, out, cnt, regions);
}